// Round 1
// baseline (399.060 us; speedup 1.0000x reference)
//
#include <hip/hip_runtime.h>
#include <hip/hip_bf16.h>

#define B_TOT 16384
#define T_LEN 512
// H = 15, padded ownership to 16 units over 8 lanes/sequence (unit 15 is all-zero)

__device__ __forceinline__ float fast_rcp(float x) { return __builtin_amdgcn_rcpf(x); }
__device__ __forceinline__ float sigm(float x) { return fast_rcp(1.0f + __expf(-x)); }
// tanh(x) = 2*sigmoid(2x) - 1 ; saturates correctly for |x| large (exp -> inf -> rcp -> 0)
__device__ __forceinline__ float tanh_f(float x) { return fmaf(2.0f, fast_rcp(1.0f + __expf(-2.0f * x)), -1.0f); }

// Broadcast value from lane (group_base + SRC) within each aligned 8-lane group.
// ds_swizzle BitMode: src_lane = (lane & 0x18) | SRC  -> imm = (SRC<<5) | 0x18
template <int SRC>
__device__ __forceinline__ float bcast8(float v) {
  return __int_as_float(__builtin_amdgcn_ds_swizzle(__float_as_int(v), (SRC << 5) | 0x18));
}

// One sequence per 8 lanes. Lane sub (=lane&7) owns hidden units u0=2*sub, u0+1.
// Each lane keeps its 8 gate rows (i,f,g,o × 2 units) of W_hh/W_ih/bias in registers.
__global__ __launch_bounds__(256, 2) void lstm_scan_kernel(
    const float* __restrict__ x, const float* __restrict__ W_ih,
    const float* __restrict__ W_hh, const float* __restrict__ b_ih,
    const float* __restrict__ b_hh, float* __restrict__ h_out) {
  const int lane = threadIdx.x & 63;
  const int wave = threadIdx.x >> 6;
  const int sub = lane & 7;   // which slice of the hidden state
  const int s = lane >> 3;    // which sequence within the wave (groups of 8 aligned)
  const int b = blockIdx.x * 32 + wave * 8 + s;
  const int u0 = sub * 2;

  // Register-resident weights: rows r = g*2 + j  (gate g in {i,f,g,o}, unit j in {0,1})
  float Whh[8][15];
  float Wih[8][3];
  float bb[8];
#pragma unroll
  for (int g = 0; g < 4; ++g) {
#pragma unroll
    for (int j = 0; j < 2; ++j) {
      const int r = g * 2 + j;
      const int u = u0 + j;
      const bool valid = (u < 15);
      const int row = g * 15 + (valid ? u : 0);
#pragma unroll
      for (int k = 0; k < 15; ++k) Whh[r][k] = valid ? W_hh[row * 15 + k] : 0.0f;
#pragma unroll
      for (int k = 0; k < 3; ++k) Wih[r][k] = valid ? W_ih[row * 3 + k] : 0.0f;
      bb[r] = valid ? (b_ih[row] + b_hh[row]) : 0.0f;
    }
  }

  float hq[15];
#pragma unroll
  for (int k = 0; k < 15; ++k) hq[k] = 0.0f;
  float c0 = 0.0f, c1 = 0.0f;
  float h0n = 0.0f, h1n = 0.0f;

  const float* xp = x + (size_t)b * (T_LEN * 3);
  // software prefetch of x[t]
  float nx0 = xp[0], nx1 = xp[1], nx2 = xp[2];

  for (int t = 0; t < T_LEN; ++t) {
    const float x0 = nx0, x1 = nx1, x2 = nx2;
    const float* np_ = xp + ((t < T_LEN - 1) ? 3 : 0);
    nx0 = np_[0];
    nx1 = np_[1];
    nx2 = np_[2];
    xp = np_;

    float acc[8];
#pragma unroll
    for (int r = 0; r < 8; ++r) {
      float a = fmaf(Wih[r][0], x0, fmaf(Wih[r][1], x1, fmaf(Wih[r][2], x2, bb[r])));
#pragma unroll
      for (int k = 0; k < 15; ++k) a = fmaf(Whh[r][k], hq[k], a);
      acc[r] = a;
    }

    const float i0 = sigm(acc[0]);
    const float i1 = sigm(acc[1]);
    const float f0 = sigm(acc[2]);
    const float f1 = sigm(acc[3]);
    const float g0 = tanh_f(acc[4]);
    const float g1 = tanh_f(acc[5]);
    const float o0 = sigm(acc[6]);
    const float o1 = sigm(acc[7]);
    c0 = fmaf(f0, c0, i0 * g0);
    c1 = fmaf(f1, c1, i1 * g1);
    h0n = o0 * tanh_f(c0);
    h1n = o1 * tanh_f(c1);

    // allgather new h across the 8-lane group (unit u -> owner sub=u>>1, j=u&1)
    hq[0] = bcast8<0>(h0n);
    hq[1] = bcast8<0>(h1n);
    hq[2] = bcast8<1>(h0n);
    hq[3] = bcast8<1>(h1n);
    hq[4] = bcast8<2>(h0n);
    hq[5] = bcast8<2>(h1n);
    hq[6] = bcast8<3>(h0n);
    hq[7] = bcast8<3>(h1n);
    hq[8] = bcast8<4>(h0n);
    hq[9] = bcast8<4>(h1n);
    hq[10] = bcast8<5>(h0n);
    hq[11] = bcast8<5>(h1n);
    hq[12] = bcast8<6>(h0n);
    hq[13] = bcast8<6>(h1n);
    hq[14] = bcast8<7>(h0n);
  }

  // write last h: [B][16] layout, column 15 zeroed
  float* hp = h_out + (size_t)b * 16;
  hp[u0] = h0n;
  hp[u0 + 1] = (u0 + 1 < 15) ? h1n : 0.0f;
}

// Head: y = relu(h @ W1^T + b1) @ W2^T + b2. Block = 256 threads handles 64 batch rows;
// each row by 4 threads (16 output units each).
__global__ __launch_bounds__(256) void head_mlp_kernel(
    const float* __restrict__ h_ws, const float* __restrict__ W1,
    const float* __restrict__ b1, const float* __restrict__ W2,
    const float* __restrict__ b2, float* __restrict__ out) {
  __shared__ float sW1[64][17];
  __shared__ float sW2[64][65];
  __shared__ float sh[64][17];
  __shared__ float sy[64][65];
  __shared__ float sb1[64];
  __shared__ float sb2[64];

  const int tid = threadIdx.x;
  for (int i = tid; i < 64 * 16; i += 256) {
    const int u = i >> 4, k = i & 15;
    sW1[u][k] = (k < 15) ? W1[u * 15 + k] : 0.0f;
  }
  if (tid < 64) {
    sb1[tid] = b1[tid];
    sb2[tid] = b2[tid];
  }
  for (int i = tid; i < 64 * 64; i += 256) sW2[i >> 6][i & 63] = W2[i];
  for (int i = tid; i < 64 * 16; i += 256) sh[i >> 4][i & 15] = h_ws[(size_t)blockIdx.x * 1024 + i];
  __syncthreads();

  const int r = tid >> 2;  // local batch row
  const int q = tid & 3;   // quarter of the 64 outputs

  // y1 = relu(W1 h + b1), units q*16 .. q*16+15
  float y1v[16];
#pragma unroll
  for (int j = 0; j < 16; ++j) {
    const int u = q * 16 + j;
    float a = sb1[u];
#pragma unroll
    for (int k = 0; k < 15; ++k) a = fmaf(sW1[u][k], sh[r][k], a);
    y1v[j] = fmaxf(a, 0.0f);
  }
#pragma unroll
  for (int j = 0; j < 16; ++j) sy[r][q * 16 + j] = y1v[j];
  __syncthreads();

  // y2 = W2 y1 + b2
  float yv[64];
#pragma unroll
  for (int k = 0; k < 64; ++k) yv[k] = sy[r][k];
  float o[16];
#pragma unroll
  for (int j = 0; j < 16; ++j) {
    const int u = q * 16 + j;
    float a = sb2[u];
#pragma unroll
    for (int k = 0; k < 64; ++k) a = fmaf(sW2[u][k], yv[k], a);
    o[j] = a;
  }

  float* op = out + ((size_t)(blockIdx.x * 64 + r)) * 64 + q * 16;
#pragma unroll
  for (int j = 0; j < 16; ++j) op[j] = o[j];
}

extern "C" void kernel_launch(void* const* d_in, const int* in_sizes, int n_in,
                              void* d_out, int out_size, void* d_ws, size_t ws_size,
                              hipStream_t stream) {
  (void)in_sizes;
  (void)n_in;
  (void)out_size;
  (void)ws_size;
  const float* x = (const float*)d_in[0];
  const float* W_ih = (const float*)d_in[1];
  const float* W_hh = (const float*)d_in[2];
  const float* b_ih = (const float*)d_in[3];
  const float* b_hh = (const float*)d_in[4];
  const float* W1 = (const float*)d_in[5];
  const float* b1 = (const float*)d_in[6];
  const float* W2 = (const float*)d_in[7];
  const float* b2 = (const float*)d_in[8];
  float* out = (float*)d_out;
  float* h_ws = (float*)d_ws;  // [B][16] floats = 1 MB

  lstm_scan_kernel<<<B_TOT / 32, 256, 0, stream>>>(x, W_ih, W_hh, b_ih, b_hh, h_ws);
  head_mlp_kernel<<<B_TOT / 64, 256, 0, stream>>>(h_ws, W1, b1, W2, b2, out);
}

// Round 2
// 376.393 us; speedup vs baseline: 1.0602x; 1.0602x over previous
//
#include <hip/hip_runtime.h>
#include <hip/hip_bf16.h>

#define B_TOT 16384
#define T_LEN 512
// H = 15, padded ownership to 16 units over 8 lanes/sequence (unit 15 is all-zero)

typedef float f32x2 __attribute__((ext_vector_type(2)));

__device__ __forceinline__ float fast_rcp(float x) { return __builtin_amdgcn_rcpf(x); }
__device__ __forceinline__ float sigm(float x) { return fast_rcp(1.0f + __expf(-x)); }
// tanh(x) = 2*sigmoid(2x) - 1 ; saturates correctly for |x| large
__device__ __forceinline__ float tanh_f(float x) { return fmaf(2.0f, fast_rcp(1.0f + __expf(-2.0f * x)), -1.0f); }

// Broadcast value from lane (group_base + SRC) within each aligned 8-lane group.
// ds_swizzle BitMode: src_lane = (lane & 0x18) | SRC  -> imm = (SRC<<5) | 0x18
template <int SRC>
__device__ __forceinline__ float bcast8(float v) {
  return __int_as_float(__builtin_amdgcn_ds_swizzle(__float_as_int(v), (SRC << 5) | 0x18));
}

// Packed dual-fp32 FMA: d = w*v + d  (element-wise on register pairs)
#define PK_FMA_ACC(d, w, v) \
  asm("v_pk_fma_f32 %0, %1, %2, %0" : "+v"(d) : "v"(w), "v"(v))
#define PK_FMA_INIT(d, w, v, c) \
  asm("v_pk_fma_f32 %0, %1, %2, %3" : "=v"(d) : "v"(w), "v"(v), "v"(c))

// One sequence per 8 lanes. Lane sub (=lane&7) owns hidden units u0=2*sub, u0+1.
// Each lane keeps its 8 gate rows (i,f,g,o x 2 units) packed as float2 pairs:
//   row r (r = gate*2 + j): 18 MACs = 9 pk_fma over shared operand vector vv[9]
//   vv[0]={x0,x1} vv[1]={x2,h0} vv[2]={h1,h2} ... vv[8]={h13,h14}
__global__ __launch_bounds__(256, 2) void lstm_scan_kernel(
    const float* __restrict__ x, const float* __restrict__ W_ih,
    const float* __restrict__ W_hh, const float* __restrict__ b_ih,
    const float* __restrict__ b_hh, float* __restrict__ h_out) {
  const int lane = threadIdx.x & 63;
  const int wave = threadIdx.x >> 6;
  const int sub = lane & 7;   // slice of the hidden state
  const int s = lane >> 3;    // sequence within the wave
  const int b = blockIdx.x * 32 + wave * 8 + s;
  const int u0 = sub * 2;

  f32x2 Wp[8][9];  // packed weights
  f32x2 Bp[8];     // {bias, 0}
#pragma unroll
  for (int g = 0; g < 4; ++g) {
#pragma unroll
    for (int j = 0; j < 2; ++j) {
      const int r = g * 2 + j;
      const int u = u0 + j;
      const bool valid = (u < 15);
      const int row = g * 15 + (valid ? u : 0);
      float wih[3];
#pragma unroll
      for (int k = 0; k < 3; ++k) wih[k] = valid ? W_ih[row * 3 + k] : 0.0f;
      float whh[15];
#pragma unroll
      for (int k = 0; k < 15; ++k) whh[k] = valid ? W_hh[row * 15 + k] : 0.0f;
      Wp[r][0].x = wih[0];
      Wp[r][0].y = wih[1];
      Wp[r][1].x = wih[2];
      Wp[r][1].y = whh[0];
#pragma unroll
      for (int jj = 2; jj < 9; ++jj) {
        Wp[r][jj].x = whh[2 * jj - 3];
        Wp[r][jj].y = whh[2 * jj - 2];
      }
      Bp[r].x = valid ? (b_ih[row] + b_hh[row]) : 0.0f;
      Bp[r].y = 0.0f;
    }
  }
  // Pin packed weights into architectural VGPRs (opaque def kills remat/AGPR shuffling)
#pragma unroll
  for (int r = 0; r < 8; ++r) {
#pragma unroll
    for (int jj = 0; jj < 9; ++jj) asm volatile("" : "+v"(Wp[r][jj]));
    asm volatile("" : "+v"(Bp[r]));
  }

  f32x2 vv[9];
#pragma unroll
  for (int jj = 0; jj < 9; ++jj) {
    vv[jj].x = 0.0f;
    vv[jj].y = 0.0f;
  }
  float c0 = 0.0f, c1 = 0.0f;
  float h0n = 0.0f, h1n = 0.0f;

  const float* xp = x + (size_t)b * (T_LEN * 3);
  float nx0 = xp[0], nx1 = xp[1], nx2 = xp[2];

  for (int t = 0; t < T_LEN; ++t) {
    vv[0].x = nx0;
    vv[0].y = nx1;
    vv[1].x = nx2;
    const float* np_ = xp + ((t < T_LEN - 1) ? 3 : 0);
    nx0 = np_[0];
    nx1 = np_[1];
    nx2 = np_[2];
    xp = np_;

    f32x2 a2[8];
#pragma unroll
    for (int r = 0; r < 8; ++r) PK_FMA_INIT(a2[r], Wp[r][0], vv[0], Bp[r]);
#pragma unroll
    for (int jj = 1; jj < 9; ++jj) {
#pragma unroll
      for (int r = 0; r < 8; ++r) PK_FMA_ACC(a2[r], Wp[r][jj], vv[jj]);
    }
    float acc[8];
#pragma unroll
    for (int r = 0; r < 8; ++r) acc[r] = a2[r].x + a2[r].y;

    const float i0 = sigm(acc[0]);
    const float i1 = sigm(acc[1]);
    const float f0 = sigm(acc[2]);
    const float f1 = sigm(acc[3]);
    const float g0 = tanh_f(acc[4]);
    const float g1 = tanh_f(acc[5]);
    const float o0 = sigm(acc[6]);
    const float o1 = sigm(acc[7]);
    c0 = fmaf(f0, c0, i0 * g0);
    c1 = fmaf(f1, c1, i1 * g1);
    h0n = o0 * tanh_f(c0);
    h1n = o1 * tanh_f(c1);

    // allgather new h into packed operand vector (unit u: owner sub=u>>1, j=u&1)
    vv[1].y = bcast8<0>(h0n);  // h0
    vv[2].x = bcast8<0>(h1n);  // h1
    vv[2].y = bcast8<1>(h0n);  // h2
    vv[3].x = bcast8<1>(h1n);  // h3
    vv[3].y = bcast8<2>(h0n);  // h4
    vv[4].x = bcast8<2>(h1n);  // h5
    vv[4].y = bcast8<3>(h0n);  // h6
    vv[5].x = bcast8<3>(h1n);  // h7
    vv[5].y = bcast8<4>(h0n);  // h8
    vv[6].x = bcast8<4>(h1n);  // h9
    vv[6].y = bcast8<5>(h0n);  // h10
    vv[7].x = bcast8<5>(h1n);  // h11
    vv[7].y = bcast8<6>(h0n);  // h12
    vv[8].x = bcast8<6>(h1n);  // h13
    vv[8].y = bcast8<7>(h0n);  // h14
  }

  // write last h: [B][16] layout, column 15 zeroed
  float* hp = h_out + (size_t)b * 16;
  hp[u0] = h0n;
  hp[u0 + 1] = (u0 + 1 < 15) ? h1n : 0.0f;
}

// Head: y = relu(h @ W1^T + b1) @ W2^T + b2. Block = 256 threads handles 64 batch rows;
// each row by 4 threads (16 output units each).
__global__ __launch_bounds__(256) void head_mlp_kernel(
    const float* __restrict__ h_ws, const float* __restrict__ W1,
    const float* __restrict__ b1, const float* __restrict__ W2,
    const float* __restrict__ b2, float* __restrict__ out) {
  __shared__ float sW1[64][17];
  __shared__ float sW2[64][65];
  __shared__ float sh[64][17];
  __shared__ float sy[64][65];
  __shared__ float sb1[64];
  __shared__ float sb2[64];

  const int tid = threadIdx.x;
  for (int i = tid; i < 64 * 16; i += 256) {
    const int u = i >> 4, k = i & 15;
    sW1[u][k] = (k < 15) ? W1[u * 15 + k] : 0.0f;
  }
  if (tid < 64) {
    sb1[tid] = b1[tid];
    sb2[tid] = b2[tid];
  }
  for (int i = tid; i < 64 * 64; i += 256) sW2[i >> 6][i & 63] = W2[i];
  for (int i = tid; i < 64 * 16; i += 256) sh[i >> 4][i & 15] = h_ws[(size_t)blockIdx.x * 1024 + i];
  __syncthreads();

  const int r = tid >> 2;  // local batch row
  const int q = tid & 3;   // quarter of the 64 outputs

  float y1v[16];
#pragma unroll
  for (int j = 0; j < 16; ++j) {
    const int u = q * 16 + j;
    float a = sb1[u];
#pragma unroll
    for (int k = 0; k < 15; ++k) a = fmaf(sW1[u][k], sh[r][k], a);
    y1v[j] = fmaxf(a, 0.0f);
  }
#pragma unroll
  for (int j = 0; j < 16; ++j) sy[r][q * 16 + j] = y1v[j];
  __syncthreads();

  float yv[64];
#pragma unroll
  for (int k = 0; k < 64; ++k) yv[k] = sy[r][k];
  float o[16];
#pragma unroll
  for (int j = 0; j < 16; ++j) {
    const int u = q * 16 + j;
    float a = sb2[u];
#pragma unroll
    for (int k = 0; k < 64; ++k) a = fmaf(sW2[u][k], yv[k], a);
    o[j] = a;
  }

  float* op = out + ((size_t)(blockIdx.x * 64 + r)) * 64 + q * 16;
#pragma unroll
  for (int j = 0; j < 16; ++j) op[j] = o[j];
}

extern "C" void kernel_launch(void* const* d_in, const int* in_sizes, int n_in,
                              void* d_out, int out_size, void* d_ws, size_t ws_size,
                              hipStream_t stream) {
  (void)in_sizes;
  (void)n_in;
  (void)out_size;
  (void)ws_size;
  const float* x = (const float*)d_in[0];
  const float* W_ih = (const float*)d_in[1];
  const float* W_hh = (const float*)d_in[2];
  const float* b_ih = (const float*)d_in[3];
  const float* b_hh = (const float*)d_in[4];
  const float* W1 = (const float*)d_in[5];
  const float* b1 = (const float*)d_in[6];
  const float* W2 = (const float*)d_in[7];
  const float* b2 = (const float*)d_in[8];
  float* out = (float*)d_out;
  float* h_ws = (float*)d_ws;  // [B][16] floats = 1 MB

  lstm_scan_kernel<<<B_TOT / 32, 256, 0, stream>>>(x, W_ih, W_hh, b_ih, b_hh, h_ws);
  head_mlp_kernel<<<B_TOT / 64, 256, 0, stream>>>(h_ws, W1, b1, W2, b2, out);
}